// Round 2
// baseline (868.320 us; speedup 1.0000x reference)
//
#include <hip/hip_runtime.h>
#include <hip/hip_bf16.h>

#define NEG 0.2f
#define SH 6                  // 64 nodes per bucket
typedef unsigned int u32;
typedef unsigned short u16;

// ---------------- bucket histogram ----------------
__global__ void bhist_k(const int* __restrict__ ei, int* __restrict__ bcnt, int E, int N){
  int e = blockIdx.x*blockDim.x + threadIdx.x;
  if (e < E) atomicAdd(&bcnt[ei[E + e] >> SH], 1);
  else if (e < E + N) atomicAdd(&bcnt[(e - E) >> SH], 1);
}

// ---------------- single-block exclusive scan over buckets (NBK <= 2048) ----------------
__global__ void bscan_k(const int* __restrict__ bcnt, int* __restrict__ bkt_off,
                        int* __restrict__ bcur, int NBK, int Etot){
  __shared__ int sd[256];
  int t = threadIdx.x;
  int v[8]; int s = 0;
  int base = t*8;
  #pragma unroll
  for (int j=0;j<8;j++){ v[j] = (base+j < NBK)? bcnt[base+j] : 0; s += v[j]; }
  sd[t] = s; __syncthreads();
  for (int o=1;o<256;o<<=1){
    int x = (t>=o)? sd[t-o] : 0; __syncthreads();
    sd[t] += x; __syncthreads();
  }
  int excl = sd[t] - s;
  #pragma unroll
  for (int j=0;j<8;j++){
    if (base+j < NBK){ bkt_off[base+j] = excl; bcur[base+j] = excl; }
    excl += v[j];
  }
  if (t == 255) bkt_off[NBK] = Etot;
}

// ---------------- phase A: scatter (src,dst) pairs into dst-buckets ----------------
__global__ void scatA_k(const int* __restrict__ ei, int* __restrict__ bcur,
                        int2* __restrict__ pairs, int E, int N){
  int e = blockIdx.x*blockDim.x + threadIdx.x;
  int s, d;
  if (e < E){ s = ei[e]; d = ei[E+e]; }
  else if (e < E + N){ s = d = e - E; }
  else return;
  int p = atomicAdd(&bcur[d >> SH], 1);
  pairs[p] = make_int2(s, d);
}

// ---------------- phase B: per-bucket local counting sort -> CSR ----------------
__global__ __launch_bounds__(256) void scatB_k(const int2* __restrict__ pairs,
                                               const int* __restrict__ bkt_off,
                                               int* __restrict__ off,
                                               int* __restrict__ ssrc,
                                               int N, int NBK, int Etot){
  __shared__ int lc[64];
  int b = blockIdx.x, t = threadIdx.x;
  int beg = bkt_off[b], end = bkt_off[b+1];
  if (t < 64) lc[t] = 0;
  __syncthreads();
  for (int k = beg + t; k < end; k += 256)
    atomicAdd(&lc[pairs[k].y & 63], 1);
  __syncthreads();
  if (t < 64){
    int c = lc[t];
    int inc = c;
    #pragma unroll
    for (int o=1;o<64;o<<=1){ int u = __shfl_up(inc, o); if (t >= o) inc += u; }
    int start = beg + inc - c;            // exclusive
    int node = (b << SH) + t;
    if (node < N) off[node] = start;
    lc[t] = start;                        // reuse as cursor
  }
  if (b == 0 && t == 0) off[N] = Etot;
  __syncthreads();
  for (int k = beg + t; k < end; k += 256){
    int2 pr = pairs[k];
    int p = atomicAdd(&lc[pr.y & 63], 1);
    ssrc[p] = pr.x;
  }
}

// ---------------- h1 = x @ W1 (fp32 compute, bf16 output) ----------------
__global__ __launch_bounds__(256) void gemm_k(const float* __restrict__ x,
                                              const float* __restrict__ W,
                                              u16* __restrict__ h1b, int N){
  __shared__ float xs[128*132];
  __shared__ float ws[128*128];
  int tid = threadIdx.x;
  #pragma unroll
  for (int i=0;i<16;i++){
    int j = i*256 + tid;
    ((float4*)ws)[j] = ((const float4*)W)[j];
  }
  int rowBase = blockIdx.x * 128;
  #pragma unroll
  for (int i=0;i<16;i++){
    int j = i*256 + tid;
    int r = j >> 5, k4 = j & 31;
    float4 v = make_float4(0.f,0.f,0.f,0.f);
    if (rowBase + r < N) v = ((const float4*)x)[(size_t)(rowBase+r)*32 + k4];
    *(float4*)&xs[r*132 + k4*4] = v;
  }
  __syncthreads();
  int ty = tid >> 4, tx = tid & 15;
  float acc[8][8];
  #pragma unroll
  for (int i=0;i<8;i++)
    #pragma unroll
    for (int j=0;j<8;j++) acc[i][j]=0.f;
  for (int k=0;k<128;k+=4){
    float4 xv[8];
    #pragma unroll
    for (int i=0;i<8;i++) xv[i] = *(float4*)&xs[(ty + 16*i)*132 + k];
    #pragma unroll
    for (int j=0;j<4;j++){
      float4 wa = *(float4*)&ws[(k+j)*128 + tx*4];
      float4 wb = *(float4*)&ws[(k+j)*128 + 64 + tx*4];
      #pragma unroll
      for (int i=0;i<8;i++){
        float xx = ((float*)&xv[i])[j];
        acc[i][0] = fmaf(xx, wa.x, acc[i][0]);
        acc[i][1] = fmaf(xx, wa.y, acc[i][1]);
        acc[i][2] = fmaf(xx, wa.z, acc[i][2]);
        acc[i][3] = fmaf(xx, wa.w, acc[i][3]);
        acc[i][4] = fmaf(xx, wb.x, acc[i][4]);
        acc[i][5] = fmaf(xx, wb.y, acc[i][5]);
        acc[i][6] = fmaf(xx, wb.z, acc[i][6]);
        acc[i][7] = fmaf(xx, wb.w, acc[i][7]);
      }
    }
  }
  #pragma unroll
  for (int i=0;i<8;i++){
    int r = rowBase + ty + 16*i;
    if (r < N){
      u32 w0, w1;
      {
        __hip_bfloat16 h0=__float2bfloat16(acc[i][0]), h1=__float2bfloat16(acc[i][1]);
        __hip_bfloat16 h2=__float2bfloat16(acc[i][2]), h3=__float2bfloat16(acc[i][3]);
        w0 = (u32)*(u16*)&h0 | ((u32)*(u16*)&h1 << 16);
        w1 = (u32)*(u16*)&h2 | ((u32)*(u16*)&h3 << 16);
      }
      *(uint2*)&h1b[(size_t)r*128 + tx*4] = make_uint2(w0, w1);
      {
        __hip_bfloat16 h0=__float2bfloat16(acc[i][4]), h1=__float2bfloat16(acc[i][5]);
        __hip_bfloat16 h2=__float2bfloat16(acc[i][6]), h3=__float2bfloat16(acc[i][7]);
        w0 = (u32)*(u16*)&h0 | ((u32)*(u16*)&h1 << 16);
        w1 = (u32)*(u16*)&h2 | ((u32)*(u16*)&h3 << 16);
      }
      *(uint2*)&h1b[(size_t)r*128 + 64 + tx*4] = make_uint2(w0, w1);
    }
  }
}

// ---------------- attention logits from bf16 h1: as1/ad1 as float2[N] ----------------
__global__ __launch_bounds__(256) void a1_k(const u32* __restrict__ h1u,
                                            const float2* __restrict__ aw_s2,
                                            const float2* __restrict__ aw_d2,
                                            float2* __restrict__ as1, float2* __restrict__ ad1, int N){
  int w = threadIdx.x >> 6, l = threadIdx.x & 63;
  int n = blockIdx.x*4 + w;
  if (n >= N) return;
  u32 hv = h1u[(size_t)n*64 + l];
  float a = __uint_as_float(hv << 16);
  float b = __uint_as_float(hv & 0xffff0000u);
  float2 sw = aw_s2[l], dw = aw_d2[l];
  float ps = a*sw.x + b*sw.y;
  float pd = a*dw.x + b*dw.y;
  #pragma unroll
  for (int o=16;o>0;o>>=1){ ps += __shfl_xor(ps,o); pd += __shfl_xor(pd,o); }
  float pso = __shfl_xor(ps, 32);
  float pdo = __shfl_xor(pd, 32);
  if (l == 0){ as1[n] = make_float2(ps, pso); ad1[n] = make_float2(pd, pdo); }
}

// ---------------- layer-1 softmax+agg fused with bias/ReLU/W2 -> h2 ----------------
__global__ __launch_bounds__(256) void agg1_k(const u32* __restrict__ h1u,
                                              const float2* __restrict__ as1,
                                              const float2* __restrict__ ad1,
                                              const int* __restrict__ off,
                                              const int* __restrict__ ssrc,
                                              const float2* __restrict__ b1_2,
                                              const float2* __restrict__ W2_2,
                                              float* __restrict__ h2, int N){
  int w = threadIdx.x >> 6, l = threadIdx.x & 63;
  int n = blockIdx.x*4 + w;
  if (n >= N) return;
  int beg = off[n], end = off[n+1];
  float2 ad = ad1[n];
  bool hsel = (l >= 32);
  float den0=0.f, den1=0.f, aca=0.f, acb=0.f;
  int s = (beg < end)? ssrc[beg] : 0;
  for (int k = beg; k < end; ++k){
    int sn = (k+1 < end)? ssrc[k+1] : 0;
    float2 av = as1[s];
    u32 hv = h1u[(size_t)s*64 + l];
    float e0 = av.x + ad.x; e0 = (e0>0.f)? e0 : NEG*e0;
    float e1 = av.y + ad.y; e1 = (e1>0.f)? e1 : NEG*e1;
    float x0 = __expf(e0), x1 = __expf(e1);
    den0 += x0; den1 += x1;
    float wgt = hsel? x1 : x0;
    float a = __uint_as_float(hv << 16);
    float b = __uint_as_float(hv & 0xffff0000u);
    aca = fmaf(wgt, a, aca); acb = fmaf(wgt, b, acb);
    s = sn;
  }
  float rd = 1.f / (hsel? den1 : den0);
  float2 bb = b1_2[l], ww = W2_2[l];
  float va = fmaxf(fmaf(aca, rd, bb.x), 0.f);
  float vb = fmaxf(fmaf(acb, rd, bb.y), 0.f);
  float p = va*ww.x + vb*ww.y;
  #pragma unroll
  for (int o=32;o>0;o>>=1) p += __shfl_xor(p,o);
  if (l == 0) h2[n] = p;
}

// ---------------- layer 2: scalar GAT + sigmoid ----------------
__global__ __launch_bounds__(256) void agg2_k(const float* __restrict__ h2,
                                              const int* __restrict__ off,
                                              const int* __restrict__ ssrc,
                                              const float* __restrict__ att_s2,
                                              const float* __restrict__ att_d2,
                                              const float* __restrict__ b2,
                                              float* __restrict__ out, int N){
  int w = threadIdx.x >> 6, l = threadIdx.x & 63;
  int n = blockIdx.x*4 + w;
  if (n >= N) return;
  float as2 = att_s2[0], ad2 = att_d2[0];
  float hd = h2[n]*ad2;
  int beg = off[n], end = off[n+1];
  float den=0.f, wsum=0.f;
  for (int k = beg + l; k < end; k += 64){
    float hs = h2[ssrc[k]];
    float e = fmaf(hs, as2, hd); e = (e>0.f)? e : NEG*e;
    float xv = __expf(e);
    den += xv; wsum = fmaf(xv, hs, wsum);
  }
  #pragma unroll
  for (int o=32;o>0;o>>=1){ den += __shfl_xor(den,o); wsum += __shfl_xor(wsum,o); }
  if (l == 0){
    float z = wsum/den + b2[0];
    out[n] = 1.f/(1.f + __expf(-z));
  }
}

extern "C" void kernel_launch(void* const* d_in, const int* in_sizes, int n_in,
                              void* d_out, int out_size, void* d_ws, size_t ws_size,
                              hipStream_t stream){
  const float* x     = (const float*)d_in[0];
  const int*   ei    = (const int*)d_in[1];
  const float* W1    = (const float*)d_in[2];
  const float* aw_s  = (const float*)d_in[3];
  const float* aw_d  = (const float*)d_in[4];
  const float* b1    = (const float*)d_in[5];
  const float* W2    = (const float*)d_in[6];
  const float* at_s2 = (const float*)d_in[7];
  const float* at_d2 = (const float*)d_in[8];
  const float* b2    = (const float*)d_in[9];
  float* out = (float*)d_out;

  const int N = in_sizes[0]/128;
  const int E = in_sizes[1]/2;
  const int Etot = E + N;
  const int NBK = (N + 63) >> SH;

  auto align256 = [](size_t v){ return (v + 255) & ~(size_t)255; };
  char* w = (char*)d_ws;
  u16* h1b      = (u16*)w;    w += align256((size_t)N*128*2);
  float2* as1   = (float2*)w; w += align256((size_t)N*8);
  float2* ad1   = (float2*)w; w += align256((size_t)N*8);
  float* h2     = (float*)w;  w += align256((size_t)N*4);
  int* off      = (int*)w;    w += align256((size_t)(N+1)*4);
  int* bcnt     = (int*)w;    w += align256((size_t)NBK*4);
  int* bkt_off  = (int*)w;    w += align256((size_t)(NBK+1)*4);
  int* bcur     = (int*)w;    w += align256((size_t)NBK*4);
  int2* pairs   = (int2*)w;   w += align256((size_t)Etot*8);
  int* ssrc     = (int*)w;    w += align256((size_t)Etot*4);

  const int tb = 256;
  hipMemsetAsync(bcnt, 0, (size_t)NBK*4, stream);
  bhist_k<<<(Etot+tb-1)/tb, tb, 0, stream>>>(ei, bcnt, E, N);
  bscan_k<<<1, 256, 0, stream>>>(bcnt, bkt_off, bcur, NBK, Etot);
  scatA_k<<<(Etot+tb-1)/tb, tb, 0, stream>>>(ei, bcur, pairs, E, N);
  scatB_k<<<NBK, 256, 0, stream>>>(pairs, bkt_off, off, ssrc, N, NBK, Etot);
  gemm_k<<<(N+127)/128, 256, 0, stream>>>(x, W1, h1b, N);
  a1_k<<<(N+3)/4, 256, 0, stream>>>((const u32*)h1b, (const float2*)aw_s, (const float2*)aw_d, as1, ad1, N);
  agg1_k<<<(N+3)/4, 256, 0, stream>>>((const u32*)h1b, as1, ad1, off, ssrc,
                                      (const float2*)b1, (const float2*)W2, h2, N);
  agg2_k<<<(N+3)/4, 256, 0, stream>>>(h2, off, ssrc, at_s2, at_d2, b2, out, N);
}

// Round 3
// 450.400 us; speedup vs baseline: 1.9279x; 1.9279x over previous
//
#include <hip/hip_runtime.h>
#include <hip/hip_bf16.h>

#define NEG 0.2f
#define NPART 8
typedef unsigned int u32;
typedef unsigned short u16;

// ---------------- XCD-partitioned per-node histogram ----------------
__global__ __launch_bounds__(256) void histp_k(const int* __restrict__ ei,
                                               int* __restrict__ cnt,
                                               int E, int N, int blocksPerPart){
  int part = blockIdx.x & (NPART-1);
  int cb   = blockIdx.x >> 3;
  int span = (N + NPART - 1) / NPART;
  int lo = part*span, hi = min(N, lo + span);
  int stride = blocksPerPart * 256;
  for (int e = cb*256 + threadIdx.x; e < E + N; e += stride){
    int d = (e < E) ? ei[E + e] : (e - E);
    if (d >= lo && d < hi) atomicAdd(&cnt[d], 1);
  }
}

// ---------------- exclusive scan (3 kernels, from round 1) ----------------
__global__ void scan1_k(const int* __restrict__ in, int* __restrict__ out,
                        int* __restrict__ bsum, int n){
  __shared__ int sd[256];
  int t = threadIdx.x;
  int base = blockIdx.x*1024 + t*4;
  int v0=0,v1=0,v2=0,v3=0;
  if (base+0 < n) v0 = in[base+0];
  if (base+1 < n) v1 = in[base+1];
  if (base+2 < n) v2 = in[base+2];
  if (base+3 < n) v3 = in[base+3];
  int s = v0+v1+v2+v3;
  sd[t] = s; __syncthreads();
  for (int o=1;o<256;o<<=1){
    int x = (t>=o)? sd[t-o] : 0; __syncthreads();
    sd[t] += x; __syncthreads();
  }
  int excl = sd[t] - s;
  if (t==255) bsum[blockIdx.x] = sd[t];
  if (base+0 < n) out[base+0] = excl;  excl += v0;
  if (base+1 < n) out[base+1] = excl;  excl += v1;
  if (base+2 < n) out[base+2] = excl;  excl += v2;
  if (base+3 < n) out[base+3] = excl;
}

__global__ void scan2_k(int* __restrict__ bsum, int nb){
  __shared__ int sd[128];
  int t = threadIdx.x;
  int v = (t<nb)? bsum[t] : 0;
  sd[t]=v; __syncthreads();
  for (int o=1;o<128;o<<=1){
    int x = (t>=o)? sd[t-o]:0; __syncthreads();
    sd[t] += x; __syncthreads();
  }
  if (t<nb) bsum[t] = sd[t]-v;
}

__global__ void addoff_k(int* __restrict__ off, const int* __restrict__ bsum,
                         int* __restrict__ cur, int n, int total){
  int i = blockIdx.x*blockDim.x + threadIdx.x;
  if (i < n){ int v = off[i] + bsum[i>>10]; off[i]=v; cur[i]=v; }
  if (i==0) off[n] = total;
}

// ---------------- XCD-partitioned scatter -> CSR ssrc ----------------
__global__ __launch_bounds__(256) void scatp_k(const int* __restrict__ ei,
                                               int* __restrict__ cur,
                                               int* __restrict__ ssrc,
                                               int E, int N, int blocksPerPart){
  int part = blockIdx.x & (NPART-1);
  int cb   = blockIdx.x >> 3;
  int span = (N + NPART - 1) / NPART;
  int lo = part*span, hi = min(N, lo + span);
  int stride = blocksPerPart * 256;
  for (int e = cb*256 + threadIdx.x; e < E + N; e += stride){
    int d = (e < E) ? ei[E + e] : (e - E);
    if (d >= lo && d < hi){
      int s = (e < E) ? ei[e] : d;
      int p = atomicAdd(&cur[d], 1);
      ssrc[p] = s;
    }
  }
}

// ---------------- h1 = x @ W1 (fp32 compute, bf16 output) ----------------
__global__ __launch_bounds__(256) void gemm_k(const float* __restrict__ x,
                                              const float* __restrict__ W,
                                              u16* __restrict__ h1b, int N){
  __shared__ float xs[128*132];
  __shared__ float ws[128*128];
  int tid = threadIdx.x;
  #pragma unroll
  for (int i=0;i<16;i++){
    int j = i*256 + tid;
    ((float4*)ws)[j] = ((const float4*)W)[j];
  }
  int rowBase = blockIdx.x * 128;
  #pragma unroll
  for (int i=0;i<16;i++){
    int j = i*256 + tid;
    int r = j >> 5, k4 = j & 31;
    float4 v = make_float4(0.f,0.f,0.f,0.f);
    if (rowBase + r < N) v = ((const float4*)x)[(size_t)(rowBase+r)*32 + k4];
    *(float4*)&xs[r*132 + k4*4] = v;
  }
  __syncthreads();
  int ty = tid >> 4, tx = tid & 15;
  float acc[8][8];
  #pragma unroll
  for (int i=0;i<8;i++)
    #pragma unroll
    for (int j=0;j<8;j++) acc[i][j]=0.f;
  for (int k=0;k<128;k+=4){
    float4 xv[8];
    #pragma unroll
    for (int i=0;i<8;i++) xv[i] = *(float4*)&xs[(ty + 16*i)*132 + k];
    #pragma unroll
    for (int j=0;j<4;j++){
      float4 wa = *(float4*)&ws[(k+j)*128 + tx*4];
      float4 wb = *(float4*)&ws[(k+j)*128 + 64 + tx*4];
      #pragma unroll
      for (int i=0;i<8;i++){
        float xx = ((float*)&xv[i])[j];
        acc[i][0] = fmaf(xx, wa.x, acc[i][0]);
        acc[i][1] = fmaf(xx, wa.y, acc[i][1]);
        acc[i][2] = fmaf(xx, wa.z, acc[i][2]);
        acc[i][3] = fmaf(xx, wa.w, acc[i][3]);
        acc[i][4] = fmaf(xx, wb.x, acc[i][4]);
        acc[i][5] = fmaf(xx, wb.y, acc[i][5]);
        acc[i][6] = fmaf(xx, wb.z, acc[i][6]);
        acc[i][7] = fmaf(xx, wb.w, acc[i][7]);
      }
    }
  }
  #pragma unroll
  for (int i=0;i<8;i++){
    int r = rowBase + ty + 16*i;
    if (r < N){
      u32 w0, w1;
      {
        __hip_bfloat16 h0=__float2bfloat16(acc[i][0]), h1=__float2bfloat16(acc[i][1]);
        __hip_bfloat16 h2=__float2bfloat16(acc[i][2]), h3=__float2bfloat16(acc[i][3]);
        w0 = (u32)*(u16*)&h0 | ((u32)*(u16*)&h1 << 16);
        w1 = (u32)*(u16*)&h2 | ((u32)*(u16*)&h3 << 16);
      }
      *(uint2*)&h1b[(size_t)r*128 + tx*4] = make_uint2(w0, w1);
      {
        __hip_bfloat16 h0=__float2bfloat16(acc[i][4]), h1=__float2bfloat16(acc[i][5]);
        __hip_bfloat16 h2=__float2bfloat16(acc[i][6]), h3=__float2bfloat16(acc[i][7]);
        w0 = (u32)*(u16*)&h0 | ((u32)*(u16*)&h1 << 16);
        w1 = (u32)*(u16*)&h2 | ((u32)*(u16*)&h3 << 16);
      }
      *(uint2*)&h1b[(size_t)r*128 + 64 + tx*4] = make_uint2(w0, w1);
    }
  }
}

// ---------------- attention logits from bf16 h1 ----------------
__global__ __launch_bounds__(256) void a1_k(const u32* __restrict__ h1u,
                                            const float2* __restrict__ aw_s2,
                                            const float2* __restrict__ aw_d2,
                                            float2* __restrict__ as1, float2* __restrict__ ad1, int N){
  int w = threadIdx.x >> 6, l = threadIdx.x & 63;
  int n = blockIdx.x*4 + w;
  if (n >= N) return;
  u32 hv = h1u[(size_t)n*64 + l];
  float a = __uint_as_float(hv << 16);
  float b = __uint_as_float(hv & 0xffff0000u);
  float2 sw = aw_s2[l], dw = aw_d2[l];
  float ps = a*sw.x + b*sw.y;
  float pd = a*dw.x + b*dw.y;
  #pragma unroll
  for (int o=16;o>0;o>>=1){ ps += __shfl_xor(ps,o); pd += __shfl_xor(pd,o); }
  float pso = __shfl_xor(ps, 32);
  float pdo = __shfl_xor(pd, 32);
  if (l == 0){ as1[n] = make_float2(ps, pso); ad1[n] = make_float2(pd, pdo); }
}

// ---------------- layer-1 softmax+agg fused with bias/ReLU/W2 -> h2 ----------------
__global__ __launch_bounds__(256) void agg1_k(const u32* __restrict__ h1u,
                                              const float2* __restrict__ as1,
                                              const float2* __restrict__ ad1,
                                              const int* __restrict__ off,
                                              const int* __restrict__ ssrc,
                                              const float2* __restrict__ b1_2,
                                              const float2* __restrict__ W2_2,
                                              float* __restrict__ h2, int N){
  int w = threadIdx.x >> 6, l = threadIdx.x & 63;
  int n = blockIdx.x*4 + w;
  if (n >= N) return;
  int beg = off[n], end = off[n+1];
  float2 ad = ad1[n];
  bool hsel = (l >= 32);
  float den0=0.f, den1=0.f, aca=0.f, acb=0.f;
  int s = (beg < end)? ssrc[beg] : 0;
  for (int k = beg; k < end; ++k){
    int sn = (k+1 < end)? ssrc[k+1] : 0;
    float2 av = as1[s];
    u32 hv = h1u[(size_t)s*64 + l];
    float e0 = av.x + ad.x; e0 = (e0>0.f)? e0 : NEG*e0;
    float e1 = av.y + ad.y; e1 = (e1>0.f)? e1 : NEG*e1;
    float x0 = __expf(e0), x1 = __expf(e1);
    den0 += x0; den1 += x1;
    float wgt = hsel? x1 : x0;
    float a = __uint_as_float(hv << 16);
    float b = __uint_as_float(hv & 0xffff0000u);
    aca = fmaf(wgt, a, aca); acb = fmaf(wgt, b, acb);
    s = sn;
  }
  float rd = 1.f / (hsel? den1 : den0);
  float2 bb = b1_2[l], ww = W2_2[l];
  float va = fmaxf(fmaf(aca, rd, bb.x), 0.f);
  float vb = fmaxf(fmaf(acb, rd, bb.y), 0.f);
  float p = va*ww.x + vb*ww.y;
  #pragma unroll
  for (int o=32;o>0;o>>=1) p += __shfl_xor(p,o);
  if (l == 0) h2[n] = p;
}

// ---------------- layer 2: scalar GAT + sigmoid ----------------
__global__ __launch_bounds__(256) void agg2_k(const float* __restrict__ h2,
                                              const int* __restrict__ off,
                                              const int* __restrict__ ssrc,
                                              const float* __restrict__ att_s2,
                                              const float* __restrict__ att_d2,
                                              const float* __restrict__ b2,
                                              float* __restrict__ out, int N){
  int w = threadIdx.x >> 6, l = threadIdx.x & 63;
  int n = blockIdx.x*4 + w;
  if (n >= N) return;
  float as2 = att_s2[0], ad2 = att_d2[0];
  float hd = h2[n]*ad2;
  int beg = off[n], end = off[n+1];
  float den=0.f, wsum=0.f;
  for (int k = beg + l; k < end; k += 64){
    float hs = h2[ssrc[k]];
    float e = fmaf(hs, as2, hd); e = (e>0.f)? e : NEG*e;
    float xv = __expf(e);
    den += xv; wsum = fmaf(xv, hs, wsum);
  }
  #pragma unroll
  for (int o=32;o>0;o>>=1){ den += __shfl_xor(den,o); wsum += __shfl_xor(wsum,o); }
  if (l == 0){
    float z = wsum/den + b2[0];
    out[n] = 1.f/(1.f + __expf(-z));
  }
}

extern "C" void kernel_launch(void* const* d_in, const int* in_sizes, int n_in,
                              void* d_out, int out_size, void* d_ws, size_t ws_size,
                              hipStream_t stream){
  const float* x     = (const float*)d_in[0];
  const int*   ei    = (const int*)d_in[1];
  const float* W1    = (const float*)d_in[2];
  const float* aw_s  = (const float*)d_in[3];
  const float* aw_d  = (const float*)d_in[4];
  const float* b1    = (const float*)d_in[5];
  const float* W2    = (const float*)d_in[6];
  const float* at_s2 = (const float*)d_in[7];
  const float* at_d2 = (const float*)d_in[8];
  const float* b2    = (const float*)d_in[9];
  float* out = (float*)d_out;

  const int N = in_sizes[0]/128;
  const int E = in_sizes[1]/2;
  const int Etot = E + N;

  auto align256 = [](size_t v){ return (v + 255) & ~(size_t)255; };
  char* w = (char*)d_ws;
  u16* h1b      = (u16*)w;    w += align256((size_t)N*128*2);
  float2* as1   = (float2*)w; w += align256((size_t)N*8);
  float2* ad1   = (float2*)w; w += align256((size_t)N*8);
  float* h2     = (float*)w;  w += align256((size_t)N*4);
  int* off      = (int*)w;    w += align256((size_t)(N+1)*4);
  int* cnt      = (int*)w;    w += align256((size_t)N*4);
  int* cur      = (int*)w;    w += align256((size_t)N*4);
  int* bsum     = (int*)w;    w += 1024;
  int* ssrc     = (int*)w;    w += align256((size_t)Etot*4);

  const int tb = 256;
  const int BPP = 128;                       // blocks per partition
  hipMemsetAsync(cnt, 0, (size_t)N*4, stream);
  histp_k<<<NPART*BPP, tb, 0, stream>>>(ei, cnt, E, N, BPP);
  int NB = (N+1023)/1024;
  scan1_k<<<NB, 256, 0, stream>>>(cnt, off, bsum, N);
  scan2_k<<<1, 128, 0, stream>>>(bsum, NB);
  addoff_k<<<(N+tb-1)/tb, tb, 0, stream>>>(off, bsum, cur, N, Etot);
  scatp_k<<<NPART*BPP, tb, 0, stream>>>(ei, cur, ssrc, E, N, BPP);
  gemm_k<<<(N+127)/128, 256, 0, stream>>>(x, W1, h1b, N);
  a1_k<<<(N+3)/4, 256, 0, stream>>>((const u32*)h1b, (const float2*)aw_s, (const float2*)aw_d, as1, ad1, N);
  agg1_k<<<(N+3)/4, 256, 0, stream>>>((const u32*)h1b, as1, ad1, off, ssrc,
                                      (const float2*)b1, (const float2*)W2, h2, N);
  agg2_k<<<(N+3)/4, 256, 0, stream>>>(h2, off, ssrc, at_s2, at_d2, b2, out, N);
}

// Round 4
// 388.836 us; speedup vs baseline: 2.2331x; 1.1583x over previous
//
#include <hip/hip_runtime.h>
#include <hip/hip_bf16.h>

#define NEG 0.2f
#define NPART 8
typedef unsigned int u32;
typedef unsigned short u16;

// ---------------- XCD-partitioned per-node histogram ----------------
__global__ __launch_bounds__(256) void histp_k(const int* __restrict__ ei,
                                               int* __restrict__ cnt,
                                               int E, int N, int blocksPerPart){
  int part = blockIdx.x & (NPART-1);
  int cb   = blockIdx.x >> 3;
  int span = (N + NPART - 1) / NPART;
  int lo = part*span, hi = min(N, lo + span);
  int stride = blocksPerPart * 256;
  for (int e = cb*256 + threadIdx.x; e < E + N; e += stride){
    int d = (e < E) ? ei[E + e] : (e - E);
    if (d >= lo && d < hi) atomicAdd(&cnt[d], 1);
  }
}

// ---------------- exclusive scan (3 kernels) ----------------
__global__ void scan1_k(const int* __restrict__ in, int* __restrict__ out,
                        int* __restrict__ bsum, int n){
  __shared__ int sd[256];
  int t = threadIdx.x;
  int base = blockIdx.x*1024 + t*4;
  int v0=0,v1=0,v2=0,v3=0;
  if (base+0 < n) v0 = in[base+0];
  if (base+1 < n) v1 = in[base+1];
  if (base+2 < n) v2 = in[base+2];
  if (base+3 < n) v3 = in[base+3];
  int s = v0+v1+v2+v3;
  sd[t] = s; __syncthreads();
  for (int o=1;o<256;o<<=1){
    int x = (t>=o)? sd[t-o] : 0; __syncthreads();
    sd[t] += x; __syncthreads();
  }
  int excl = sd[t] - s;
  if (t==255) bsum[blockIdx.x] = sd[t];
  if (base+0 < n) out[base+0] = excl;  excl += v0;
  if (base+1 < n) out[base+1] = excl;  excl += v1;
  if (base+2 < n) out[base+2] = excl;  excl += v2;
  if (base+3 < n) out[base+3] = excl;
}

__global__ void scan2_k(int* __restrict__ bsum, int nb){
  __shared__ int sd[128];
  int t = threadIdx.x;
  int v = (t<nb)? bsum[t] : 0;
  sd[t]=v; __syncthreads();
  for (int o=1;o<128;o<<=1){
    int x = (t>=o)? sd[t-o]:0; __syncthreads();
    sd[t] += x; __syncthreads();
  }
  if (t<nb) bsum[t] = sd[t]-v;
}

__global__ void addoff_k(int* __restrict__ off, const int* __restrict__ bsum,
                         int* __restrict__ cur, int n, int total){
  int i = blockIdx.x*blockDim.x + threadIdx.x;
  if (i < n){ int v = off[i] + bsum[i>>10]; off[i]=v; cur[i]=v; }
  if (i==0) off[n] = total;
}

// ---------------- XCD-partitioned scatter -> CSR ssrc ----------------
__global__ __launch_bounds__(256) void scatp_k(const int* __restrict__ ei,
                                               int* __restrict__ cur,
                                               int* __restrict__ ssrc,
                                               int E, int N, int blocksPerPart){
  int part = blockIdx.x & (NPART-1);
  int cb   = blockIdx.x >> 3;
  int span = (N + NPART - 1) / NPART;
  int lo = part*span, hi = min(N, lo + span);
  int stride = blocksPerPart * 256;
  for (int e = cb*256 + threadIdx.x; e < E + N; e += stride){
    int d = (e < E) ? ei[E + e] : (e - E);
    if (d >= lo && d < hi){
      int s = (e < E) ? ei[e] : d;
      int p = atomicAdd(&cur[d], 1);
      ssrc[p] = s;
    }
  }
}

// ---------------- h1 = x @ W1 (fp32 compute, bf16 output) ----------------
__global__ __launch_bounds__(256) void gemm_k(const float* __restrict__ x,
                                              const float* __restrict__ W,
                                              u16* __restrict__ h1b, int N){
  __shared__ float xs[128*132];
  __shared__ float ws[128*128];
  int tid = threadIdx.x;
  #pragma unroll
  for (int i=0;i<16;i++){
    int j = i*256 + tid;
    ((float4*)ws)[j] = ((const float4*)W)[j];
  }
  int rowBase = blockIdx.x * 128;
  #pragma unroll
  for (int i=0;i<16;i++){
    int j = i*256 + tid;
    int r = j >> 5, k4 = j & 31;
    float4 v = make_float4(0.f,0.f,0.f,0.f);
    if (rowBase + r < N) v = ((const float4*)x)[(size_t)(rowBase+r)*32 + k4];
    *(float4*)&xs[r*132 + k4*4] = v;
  }
  __syncthreads();
  int ty = tid >> 4, tx = tid & 15;
  float acc[8][8];
  #pragma unroll
  for (int i=0;i<8;i++)
    #pragma unroll
    for (int j=0;j<8;j++) acc[i][j]=0.f;
  for (int k=0;k<128;k+=4){
    float4 xv[8];
    #pragma unroll
    for (int i=0;i<8;i++) xv[i] = *(float4*)&xs[(ty + 16*i)*132 + k];
    #pragma unroll
    for (int j=0;j<4;j++){
      float4 wa = *(float4*)&ws[(k+j)*128 + tx*4];
      float4 wb = *(float4*)&ws[(k+j)*128 + 64 + tx*4];
      #pragma unroll
      for (int i=0;i<8;i++){
        float xx = ((float*)&xv[i])[j];
        acc[i][0] = fmaf(xx, wa.x, acc[i][0]);
        acc[i][1] = fmaf(xx, wa.y, acc[i][1]);
        acc[i][2] = fmaf(xx, wa.z, acc[i][2]);
        acc[i][3] = fmaf(xx, wa.w, acc[i][3]);
        acc[i][4] = fmaf(xx, wb.x, acc[i][4]);
        acc[i][5] = fmaf(xx, wb.y, acc[i][5]);
        acc[i][6] = fmaf(xx, wb.z, acc[i][6]);
        acc[i][7] = fmaf(xx, wb.w, acc[i][7]);
      }
    }
  }
  #pragma unroll
  for (int i=0;i<8;i++){
    int r = rowBase + ty + 16*i;
    if (r < N){
      u32 w0, w1;
      {
        __hip_bfloat16 h0=__float2bfloat16(acc[i][0]), h1=__float2bfloat16(acc[i][1]);
        __hip_bfloat16 h2=__float2bfloat16(acc[i][2]), h3=__float2bfloat16(acc[i][3]);
        w0 = (u32)*(u16*)&h0 | ((u32)*(u16*)&h1 << 16);
        w1 = (u32)*(u16*)&h2 | ((u32)*(u16*)&h3 << 16);
      }
      *(uint2*)&h1b[(size_t)r*128 + tx*4] = make_uint2(w0, w1);
      {
        __hip_bfloat16 h0=__float2bfloat16(acc[i][4]), h1=__float2bfloat16(acc[i][5]);
        __hip_bfloat16 h2=__float2bfloat16(acc[i][6]), h3=__float2bfloat16(acc[i][7]);
        w0 = (u32)*(u16*)&h0 | ((u32)*(u16*)&h1 << 16);
        w1 = (u32)*(u16*)&h2 | ((u32)*(u16*)&h3 << 16);
      }
      *(uint2*)&h1b[(size_t)r*128 + 64 + tx*4] = make_uint2(w0, w1);
    }
  }
}

// ---------------- attention logits from bf16 h1 ----------------
__global__ __launch_bounds__(256) void a1_k(const u32* __restrict__ h1u,
                                            const float2* __restrict__ aw_s2,
                                            const float2* __restrict__ aw_d2,
                                            float2* __restrict__ as1, float2* __restrict__ ad1, int N){
  int w = threadIdx.x >> 6, l = threadIdx.x & 63;
  int n = blockIdx.x*4 + w;
  if (n >= N) return;
  u32 hv = h1u[(size_t)n*64 + l];
  float a = __uint_as_float(hv << 16);
  float b = __uint_as_float(hv & 0xffff0000u);
  float2 sw = aw_s2[l], dw = aw_d2[l];
  float ps = a*sw.x + b*sw.y;
  float pd = a*dw.x + b*dw.y;
  #pragma unroll
  for (int o=16;o>0;o>>=1){ ps += __shfl_xor(ps,o); pd += __shfl_xor(pd,o); }
  float pso = __shfl_xor(ps, 32);
  float pdo = __shfl_xor(pd, 32);
  if (l == 0){ as1[n] = make_float2(ps, pso); ad1[n] = make_float2(pd, pdo); }
}

// ---------------- per-edge softmax weights (edge-parallel per node) ----------------
__global__ __launch_bounds__(256) void wexp_k(const float2* __restrict__ as1,
                                              const float2* __restrict__ ad1,
                                              const int* __restrict__ off,
                                              const int* __restrict__ ssrc,
                                              float2* __restrict__ wexp, int N){
  int w = threadIdx.x >> 6, l = threadIdx.x & 63;
  int n = blockIdx.x*4 + w;
  if (n >= N) return;
  int beg = off[n], end = off[n+1];
  float2 ad = ad1[n];
  for (int k = beg + l; k < end; k += 64){
    float2 av = as1[ssrc[k]];
    float e0 = av.x + ad.x; e0 = (e0>0.f)? e0 : NEG*e0;
    float e1 = av.y + ad.y; e1 = (e1>0.f)? e1 : NEG*e1;
    wexp[k] = make_float2(__expf(e0), __expf(e1));
  }
}

// ---------------- layer-1 aggregation: 8-wide gather pipeline ----------------
__global__ __launch_bounds__(256) void agg1_k(const u32* __restrict__ h1u,
                                              const float2* __restrict__ wexp,
                                              const int* __restrict__ off,
                                              const int* __restrict__ ssrc,
                                              const float2* __restrict__ b1_2,
                                              const float2* __restrict__ W2_2,
                                              float* __restrict__ h2, int N){
  int w = threadIdx.x >> 6, l = threadIdx.x & 63;
  int n = blockIdx.x*4 + w;
  if (n >= N) return;
  int beg = off[n], end = off[n+1];
  bool hsel = (l >= 32);
  float den = 0.f, aca = 0.f, acb = 0.f;
  for (int kk = beg; kk < end; kk += 8){
    int sx[8]; float gx[8];
    #pragma unroll
    for (int j=0;j<8;j++){
      int idx = kk + j;
      bool v = idx < end;
      idx = v ? idx : end-1;
      sx[j] = ssrc[idx];
      float2 wv = wexp[idx];
      float g = hsel ? wv.y : wv.x;
      gx[j] = v ? g : 0.f;
    }
    u32 hv[8];
    #pragma unroll
    for (int j=0;j<8;j++) hv[j] = h1u[(size_t)sx[j]*64 + l];
    #pragma unroll
    for (int j=0;j<8;j++){
      float a = __uint_as_float(hv[j] << 16);
      float b = __uint_as_float(hv[j] & 0xffff0000u);
      den += gx[j];
      aca = fmaf(gx[j], a, aca);
      acb = fmaf(gx[j], b, acb);
    }
  }
  float rd = 1.f / den;
  float2 bb = b1_2[l], ww = W2_2[l];
  float va = fmaxf(fmaf(aca, rd, bb.x), 0.f);
  float vb = fmaxf(fmaf(acb, rd, bb.y), 0.f);
  float p = va*ww.x + vb*ww.y;
  #pragma unroll
  for (int o=32;o>0;o>>=1) p += __shfl_xor(p,o);
  if (l == 0) h2[n] = p;
}

// ---------------- layer 2: scalar GAT + sigmoid ----------------
__global__ __launch_bounds__(256) void agg2_k(const float* __restrict__ h2,
                                              const int* __restrict__ off,
                                              const int* __restrict__ ssrc,
                                              const float* __restrict__ att_s2,
                                              const float* __restrict__ att_d2,
                                              const float* __restrict__ b2,
                                              float* __restrict__ out, int N){
  int w = threadIdx.x >> 6, l = threadIdx.x & 63;
  int n = blockIdx.x*4 + w;
  if (n >= N) return;
  float as2 = att_s2[0], ad2 = att_d2[0];
  float hd = h2[n]*ad2;
  int beg = off[n], end = off[n+1];
  float den=0.f, wsum=0.f;
  for (int k = beg + l; k < end; k += 64){
    float hs = h2[ssrc[k]];
    float e = fmaf(hs, as2, hd); e = (e>0.f)? e : NEG*e;
    float xv = __expf(e);
    den += xv; wsum = fmaf(xv, hs, wsum);
  }
  #pragma unroll
  for (int o=32;o>0;o>>=1){ den += __shfl_xor(den,o); wsum += __shfl_xor(wsum,o); }
  if (l == 0){
    float z = wsum/den + b2[0];
    out[n] = 1.f/(1.f + __expf(-z));
  }
}

extern "C" void kernel_launch(void* const* d_in, const int* in_sizes, int n_in,
                              void* d_out, int out_size, void* d_ws, size_t ws_size,
                              hipStream_t stream){
  const float* x     = (const float*)d_in[0];
  const int*   ei    = (const int*)d_in[1];
  const float* W1    = (const float*)d_in[2];
  const float* aw_s  = (const float*)d_in[3];
  const float* aw_d  = (const float*)d_in[4];
  const float* b1    = (const float*)d_in[5];
  const float* W2    = (const float*)d_in[6];
  const float* at_s2 = (const float*)d_in[7];
  const float* at_d2 = (const float*)d_in[8];
  const float* b2    = (const float*)d_in[9];
  float* out = (float*)d_out;

  const int N = in_sizes[0]/128;
  const int E = in_sizes[1]/2;
  const int Etot = E + N;

  auto align256 = [](size_t v){ return (v + 255) & ~(size_t)255; };
  char* w = (char*)d_ws;
  u16* h1b      = (u16*)w;    w += align256((size_t)N*128*2);
  float2* as1   = (float2*)w; w += align256((size_t)N*8);
  float2* ad1   = (float2*)w; w += align256((size_t)N*8);
  float* h2     = (float*)w;  w += align256((size_t)N*4);
  int* off      = (int*)w;    w += align256((size_t)(N+1)*4);
  int* cnt      = (int*)w;    w += align256((size_t)N*4);
  int* cur      = (int*)w;    w += align256((size_t)N*4);
  int* bsum     = (int*)w;    w += 1024;
  int* ssrc     = (int*)w;    w += align256((size_t)Etot*4);
  float2* wexp  = (float2*)w; w += align256((size_t)Etot*8);

  const int tb = 256;
  const int BPP = 128;
  hipMemsetAsync(cnt, 0, (size_t)N*4, stream);
  gemm_k<<<(N+127)/128, 256, 0, stream>>>(x, W1, h1b, N);
  a1_k<<<(N+3)/4, 256, 0, stream>>>((const u32*)h1b, (const float2*)aw_s, (const float2*)aw_d, as1, ad1, N);
  histp_k<<<NPART*BPP, tb, 0, stream>>>(ei, cnt, E, N, BPP);
  int NB = (N+1023)/1024;
  scan1_k<<<NB, 256, 0, stream>>>(cnt, off, bsum, N);
  scan2_k<<<1, 128, 0, stream>>>(bsum, NB);
  addoff_k<<<(N+tb-1)/tb, tb, 0, stream>>>(off, bsum, cur, N, Etot);
  scatp_k<<<NPART*BPP, tb, 0, stream>>>(ei, cur, ssrc, E, N, BPP);
  wexp_k<<<(N+3)/4, 256, 0, stream>>>(as1, ad1, off, ssrc, wexp, N);
  agg1_k<<<(N+3)/4, 256, 0, stream>>>((const u32*)h1b, wexp, off, ssrc,
                                      (const float2*)b1, (const float2*)W2, h2, N);
  agg2_k<<<(N+3)/4, 256, 0, stream>>>(h2, off, ssrc, at_s2, at_d2, b2, out, N);
}